// Round 13
// baseline (371.517 us; speedup 1.0000x reference)
//
#include <hip/hip_runtime.h>
#include <hip/hip_bf16.h>

// Problem constants (B,S,E,H,L,DFF) = (2,2048,512,8,2,2048), D=64
constexpr int BB   = 2;
constexpr int SS   = 2048;
constexpr int EE   = 512;
constexpr int HH   = 8;
constexpr int DD   = 64;
constexpr int DFF_ = 2048;
constexpr int NTOK = BB * SS;          // 4096 tokens
constexpr int NE   = NTOK * EE;        // 2097152
constexpr float EPSF  = 1e-5f;
constexpr float SCL2  = 0.125f * 1.44269504088896f;  // 1/sqrt(D) * log2(e)
constexpr float MBIAS = -1e30f;
constexpr int KSPLIT = 4;              // attention split-K parts
constexpr int KHALF  = SS / KSPLIT;    // 512

typedef __bf16 v8bf __attribute__((ext_vector_type(8)));
typedef __bf16 v4bf __attribute__((ext_vector_type(4)));
typedef float  v4f  __attribute__((ext_vector_type(4)));

__device__ __forceinline__ float bf2f(unsigned short u) {
    return __uint_as_float(((unsigned int)u) << 16);
}
__device__ __forceinline__ float bf2f(__bf16 u) {
    unsigned short us = __builtin_bit_cast(unsigned short, u);
    return __uint_as_float(((unsigned int)us) << 16);
}
// adaptive load: f=1 -> float32 buffer, f=0 -> bf16 buffer
__device__ __forceinline__ float ldA(const void* p, size_t i, int f) {
    return f ? ((const float*)p)[i] : bf2f(((const unsigned short*)p)[i]);
}
// async global->LDS, 16 B per lane (m97-verified path)
__device__ __forceinline__ void gll16(const void* g, void* l) {
    __builtin_amdgcn_global_load_lds(
        (const __attribute__((address_space(1))) void*)g,
        (__attribute__((address_space(3))) void*)l, 16, 0, 0);
}

// --------------------------------------------------------------- dtype sniff
__global__ void sniff_kernel(const unsigned short* __restrict__ x, int* flag) {
    __shared__ int cnt[256];
    int t = threadIdx.x, bad = 0;
    for (int i = t; i < 4096; i += 256) {
        float v = bf2f(x[i]);
        if (!(fabsf(v) < 1000.f)) bad++;
    }
    cnt[t] = bad;
    __syncthreads();
    if (t == 0) {
        int s = 0;
        for (int i = 0; i < 256; ++i) s += cnt[i];
        *flag = (s > 8) ? 1 : 0;           // 1 = inputs are float32
    }
}

// --------------------------------------------------------------- cvt x -> f32
__global__ void cvt_kernel(const void* __restrict__ in, float* __restrict__ out,
                           int n, const int* __restrict__ flagp) {
    const int f = *flagp;
    int i = (blockIdx.x * blockDim.x + threadIdx.x) * 4;
    if (i >= n) return;
    if (f) {
        *(float4*)(out + i) = *(const float4*)((const float*)in + i);
    } else {
        ushort4 u = *(const ushort4*)((const unsigned short*)in + i);
        out[i + 0] = bf2f(u.x); out[i + 1] = bf2f(u.y);
        out[i + 2] = bf2f(u.z); out[i + 3] = bf2f(u.w);
    }
}

// --------------------------------------------------------------- all weights -> bf16 (one launch)
__global__ void wcvt_all(const void* __restrict__ wq, const void* __restrict__ wk,
                         const void* __restrict__ wv, const void* __restrict__ W1,
                         const void* __restrict__ W2, __bf16* __restrict__ out,
                         const int* __restrict__ flagp) {
    const int f = *flagp;
    const int i = (blockIdx.x * blockDim.x + threadIdx.x) * 8;
    constexpr int n1 = 2 * EE * EE;      // 524288 per QKV tensor
    constexpr int nf = DFF_ * EE;        // 1048576 per FFN tensor
    const void* src; int off;
    if      (i < n1)          { src = wq; off = i; }
    else if (i < 2 * n1)      { src = wk; off = i - n1; }
    else if (i < 3 * n1)      { src = wv; off = i - 2 * n1; }
    else if (i < 3 * n1 + nf) { src = W1; off = i - 3 * n1; }
    else                      { src = W2; off = i - 3 * n1 - nf; }
    if (f) {
        const float* p = (const float*)src + off;
        #pragma unroll
        for (int j = 0; j < 8; ++j) out[i + j] = (__bf16)p[j];
    } else {
        *(uint4*)(out + i) = *(const uint4*)((const unsigned short*)src + off);
    }
}

// --------------------------------------------------------------- layernorm (single)
__global__ __launch_bounds__(256) void ln_kernel(
    const float* __restrict__ src,
    const void* __restrict__ g, const void* __restrict__ b,
    __bf16* __restrict__ dstb, void* __restrict__ outp,
    const int* __restrict__ flagp)
{
    const int f = *flagp;
    const int row = blockIdx.x, t = threadIdx.x;
    const float* x = src + (size_t)row * EE;
    float v0 = x[t], v1 = x[t + 256];
    float s = v0 + v1, q = v0 * v0 + v1 * v1;
    #pragma unroll
    for (int off = 32; off > 0; off >>= 1) {
        s += __shfl_down(s, off, 64);
        q += __shfl_down(q, off, 64);
    }
    __shared__ float red[8], st[2];
    const int wid = t >> 6;
    if ((t & 63) == 0) { red[wid] = s; red[4 + wid] = q; }
    __syncthreads();
    if (t == 0) {
        float S_ = red[0] + red[1] + red[2] + red[3];
        float Q_ = red[4] + red[5] + red[6] + red[7];
        float mu = S_ / EE;
        st[0] = mu;
        st[1] = rsqrtf(Q_ / EE - mu * mu + EPSF);
    }
    __syncthreads();
    const float mu = st[0], rs = st[1];
    float o0 = (v0 - mu) * rs, o1 = (v1 - mu) * rs;
    if (g) {
        o0 = o0 * ldA(g, t, f)       + ldA(b, t, f);
        o1 = o1 * ldA(g, t + 256, f) + ldA(b, t + 256, f);
    }
    const size_t i0 = (size_t)row * EE + t, i1 = i0 + 256;
    if (dstb) { dstb[i0] = (__bf16)o0; dstb[i1] = (__bf16)o1; }
    if (outp) {
        if (f) { ((float*)outp)[i0] = o0; ((float*)outp)[i1] = o1; }
        else {
            ((__hip_bfloat16*)outp)[i0] = __float2bfloat16(o0);
            ((__hip_bfloat16*)outp)[i1] = __float2bfloat16(o1);
        }
    }
}

// --------------------------------------------------------------- combine + residual + double LN
// Merges KSPLIT attention partials (raw sums / l-sums), then:
// x += LN(att,g2,b2); Hb = LN_noaffine(x)
__global__ __launch_bounds__(256) void combine_ln(
    const __bf16* __restrict__ Opart, const float* __restrict__ MLl,
    const void* __restrict__ g2, const void* __restrict__ b2,
    float* __restrict__ X, __bf16* __restrict__ Hb,
    const int* __restrict__ flagp)
{
    const int f = *flagp;
    const int tok = blockIdx.x, t = threadIdx.x;
    const int b = tok >> 11, s_ = tok & 2047;
    __shared__ float cinv[8];
    __shared__ float red[8], st[2];
    if (t < 8) {
        float l = 0.f;
        #pragma unroll
        for (int zz = 0; zz < KSPLIT; ++zz)
            l += MLl[(size_t)(zz * 16 + b * 8 + t) * SS + s_];
        cinv[t] = (l > 0.f) ? 1.f / l : 0.f;
    }
    __syncthreads();
    float a0 = 0.f, a1 = 0.f;
    {
        int c = t, h = c >> 6, d = c & 63;
        #pragma unroll
        for (int zz = 0; zz < KSPLIT; ++zz)
            a0 += bf2f(Opart[((size_t)(zz * 16 + b * 8 + h) * SS + s_) * 64 + d]);
        a0 *= cinv[h];
        c = t + 256; h = c >> 6; d = c & 63;
        #pragma unroll
        for (int zz = 0; zz < KSPLIT; ++zz)
            a1 += bf2f(Opart[((size_t)(zz * 16 + b * 8 + h) * SS + s_) * 64 + d]);
        a1 *= cinv[h];
    }
    const int wid = t >> 6;
    {
        float s = a0 + a1, q = a0 * a0 + a1 * a1;
        #pragma unroll
        for (int off = 32; off > 0; off >>= 1) {
            s += __shfl_down(s, off, 64);
            q += __shfl_down(q, off, 64);
        }
        if ((t & 63) == 0) { red[wid] = s; red[4 + wid] = q; }
    }
    __syncthreads();
    if (t == 0) {
        float S_ = red[0] + red[1] + red[2] + red[3];
        float Q_ = red[4] + red[5] + red[6] + red[7];
        float mu = S_ / EE;
        st[0] = mu;
        st[1] = rsqrtf(Q_ / EE - mu * mu + EPSF);
    }
    __syncthreads();
    const float mu1 = st[0], rs1 = st[1];
    const size_t i0 = (size_t)tok * EE + t, i1 = i0 + 256;
    float l0v = (a0 - mu1) * rs1 * ldA(g2, t, f)       + ldA(b2, t, f);
    float l1v = (a1 - mu1) * rs1 * ldA(g2, t + 256, f) + ldA(b2, t + 256, f);
    float x0 = X[i0] + l0v, x1 = X[i1] + l1v;
    __syncthreads();
    {
        float s = x0 + x1, q = x0 * x0 + x1 * x1;
        #pragma unroll
        for (int off = 32; off > 0; off >>= 1) {
            s += __shfl_down(s, off, 64);
            q += __shfl_down(q, off, 64);
        }
        if ((t & 63) == 0) { red[wid] = s; red[4 + wid] = q; }
    }
    __syncthreads();
    if (t == 0) {
        float S_ = red[0] + red[1] + red[2] + red[3];
        float Q_ = red[4] + red[5] + red[6] + red[7];
        float mu = S_ / EE;
        st[0] = mu;
        st[1] = rsqrtf(Q_ / EE - mu * mu + EPSF);
    }
    __syncthreads();
    const float mu2 = st[0], rs2 = st[1];
    X[i0] = x0; X[i1] = x1;
    Hb[i0] = (__bf16)((x0 - mu2) * rs2);
    Hb[i1] = (__bf16)((x1 - mu2) * rs2);
}

// --------------------------------------------------------------- MFMA GEMM (NT), 128x128, double-buffered
// C[m,n] = sum_k A[m,k]*W[n,k] (+bias[n]). BK=32, 4 waves 2x2 (wave tile 64x64:
// 8 ds_read_b128 per 16 MFMA = 0.5 reads/MFMA).
// flags: 1=relu | 2=f32 accumulate into Cf | 4=split-K over z (atomic, bias z==0)
// | 8=z==2 writes V^T [bh*64+d][s] with s PERMUTED within each 64-block:
//   slot(s) = (s&32) + ((s>>2)&3)*8 + ((s>>4)&1)*4 + (s&3)
//   (inverse of the PV B-operand consumption order — see attn_mfma).
__global__ __launch_bounds__(256) void gemm_mfma(
    const __bf16* __restrict__ A,
    const __bf16* Wa, const __bf16* Wb, const __bf16* Wc,
    const void* ba, const void* bb, const void* bc,
    __bf16* oa, __bf16* ob, __bf16* oc,
    float* __restrict__ Cf,
    int M, int N, int K, int flags,
    size_t welem_off, size_t belem_off, const int* __restrict__ flagp)
{
    const int f = *flagp;
    const int z = blockIdx.z;
    const __bf16* W = (z == 0) ? Wa : (z == 1) ? Wb : Wc;
    const void* bias = (z == 0) ? ba : (z == 1) ? bb : bc;
    __bf16* Cb = (z == 0) ? oa : (z == 1) ? ob : oc;
    W += welem_off;
    int kbeg = 0, kend = K;
    if (flags & 4) {
        const int ks = K >> 2;
        kbeg = z * ks; kend = kbeg + ks;
        if (z != 0) bias = nullptr;
    }

    __shared__ __bf16 As[2][128 * 32];   // 2 x 8 KB
    __shared__ __bf16 Bs[2][128 * 32];   // 2 x 8 KB
    const int t = threadIdx.x;
    const int w = t >> 6, lane = t & 63;
    const int quad = lane >> 4, l16 = lane & 15;
    const int wr = w >> 1, wc = w & 1;
    const int bm = blockIdx.x * 128, bn = blockIdx.y * 128;

    v4f acc[4][4] = {};
    const int c0 = t, c1 = t + 256;          // 512 16B chunks per tile
    const int r0 = c0 >> 2, e0 = (c0 & 3) * 8;
    const int r1 = c1 >> 2, e1 = (c1 & 3) * 8;

    // stage tile kbeg into buffer 0
    gll16(A + (size_t)(bm + r0) * K + kbeg + e0, (char*)As[0] + c0 * 16);
    gll16(A + (size_t)(bm + r1) * K + kbeg + e1, (char*)As[0] + c1 * 16);
    gll16(W + (size_t)(bn + r0) * K + kbeg + e0, (char*)Bs[0] + c0 * 16);
    gll16(W + (size_t)(bn + r1) * K + kbeg + e1, (char*)Bs[0] + c1 * 16);

    int p = 0;
    for (int k0 = kbeg; k0 < kend; k0 += 32) {
        __syncthreads();   // tile p staged (vmcnt drained at barrier); p^1 reads done
        if (k0 + 32 < kend) {
            const int kn = k0 + 32, q_ = p ^ 1;
            gll16(A + (size_t)(bm + r0) * K + kn + e0, (char*)As[q_] + c0 * 16);
            gll16(A + (size_t)(bm + r1) * K + kn + e1, (char*)As[q_] + c1 * 16);
            gll16(W + (size_t)(bn + r0) * K + kn + e0, (char*)Bs[q_] + c0 * 16);
            gll16(W + (size_t)(bn + r1) * K + kn + e1, (char*)Bs[q_] + c1 * 16);
        }
        v8bf af[4], bfr[4];
        #pragma unroll
        for (int i = 0; i < 4; ++i) {
            int row = wr * 64 + i * 16 + l16;
            af[i] = *(const v8bf*)&As[p][row * 32 + quad * 8];
        }
        #pragma unroll
        for (int j = 0; j < 4; ++j) {
            int row = wc * 64 + j * 16 + l16;
            bfr[j] = *(const v8bf*)&Bs[p][row * 32 + quad * 8];
        }
        #pragma unroll
        for (int i = 0; i < 4; ++i)
            #pragma unroll
            for (int j = 0; j < 4; ++j)
                acc[i][j] = __builtin_amdgcn_mfma_f32_16x16x32_bf16(
                    af[i], bfr[j], acc[i][j], 0, 0, 0);
        p ^= 1;
    }

    float bvv[4];
    #pragma unroll
    for (int j = 0; j < 4; ++j) {
        int col = bn + wc * 64 + j * 16 + l16;
        bvv[j] = bias ? ldA(bias, belem_off + col, f) : 0.f;
    }

    if ((flags & 8) && z == 2) {
        // V^T write with per-64-block s-permutation:
        // slot(s) = (s&32) + ((s>>2)&3)*8 + ((s>>4)&1)*4 + (s&3); r adds to low bits.
        #pragma unroll
        for (int i = 0; i < 4; ++i) {
            const int row0 = bm + wr * 64 + i * 16 + quad * 4;  // token (r=0)
            const int b_ = row0 >> 11, sl = row0 & 2047;
            const int s64 = sl & ~63, sloc = sl & 63;
            const int slot = (sloc & 32) + ((sloc >> 2) & 3) * 8 + ((sloc >> 4) & 1) * 4;
            #pragma unroll
            for (int j = 0; j < 4; ++j) {
                const int col = bn + wc * 64 + j * 16 + l16;
                const int h_ = col >> 6, d_ = col & 63;
                v4bf u;
                #pragma unroll
                for (int r = 0; r < 4; ++r) u[r] = (__bf16)(acc[i][j][r] + bvv[j]);
                *(v4bf*)(Cb + ((size_t)((b_ * 8 + h_) * 64 + d_)) * SS + s64 + slot) = u;
            }
        }
        return;
    }

    #pragma unroll
    for (int i = 0; i < 4; ++i) {
        const int rowb = bm + wr * 64 + i * 16 + quad * 4;
        #pragma unroll
        for (int j = 0; j < 4; ++j) {
            const int col = bn + wc * 64 + j * 16 + l16;
            #pragma unroll
            for (int r = 0; r < 4; ++r) {
                float v = acc[i][j][r] + bvv[j];
                if (flags & 1) v = fmaxf(v, 0.f);
                const size_t idx = (size_t)(rowb + r) * N + col;
                if (flags & 4)      unsafeAtomicAdd(&Cf[idx], v);
                else if (flags & 2) Cf[idx] += v;
                else                Cb[idx] = (__bf16)v;
            }
        }
    }
}

// --------------------------------------------------------------- MFMA attention
// Transposed dataflow (S^T = K*Q^T), split-K x4, no max-tracking (bounded
// scores), PERMUTED-V (QK^T output registers ARE the PV B-operand; P never
// touches LDS). 2048 blocks = 8/CU. The R10/R11 lesson: KSPLIT=4 needs
// `#pragma unroll 1` (else compiler unrolls the 8-iter loop -> VGPR 96) and
// NATURAL allocation (forcing 8 waves/EU -> VGPR 32 -> scratch spill,
// 468 MB HBM). This is the untested correct combination: VGPR ~52,
// LDS 18.7 KB -> 8 blocks/CU.
__global__ __launch_bounds__(256) void attn_mfma(
    const __bf16* __restrict__ Qg, const __bf16* __restrict__ Kg,
    const __bf16* __restrict__ Vtg, const int* __restrict__ mask,
    __bf16* __restrict__ Opart, float* __restrict__ MLl)
{
    __shared__ __bf16 Ks[64][72];     // [token][d]  (true s order)
    __shared__ __bf16 Vs[64][72];     // [d][slot]   (permuted s)
    __shared__ float  mkf[64];

    const int t = threadIdx.x;
    const int w = t >> 6, lane = t & 63;
    const int quad = lane >> 4, l16 = lane & 15;
    const int bh = blockIdx.y, b = bh >> 3, h = bh & 7;
    const int q0 = blockIdx.x * 64;
    const int z  = blockIdx.z;
    const int kof = z * KHALF;

    // Q fragments (B-operand of S^T: n=l16 -> q-row, k=quad*8+j -> d)
    const __bf16* qrow = Qg + ((size_t)(b * SS + q0 + w * 16 + l16)) * EE + h * DD + quad * 8;
    const v8bf qa0 = *(const v8bf*)qrow;
    const v8bf qa1 = *(const v8bf*)(qrow + 32);

    // loader mapping: row lr (0..63), 16-elem chunk lc
    const int lr = t >> 2, lc = (t & 3) * 16;
    const __bf16* kbase = Kg  + ((size_t)(b * SS + kof + lr)) * EE + h * DD + lc;
    const __bf16* vbase = Vtg + ((size_t)((b * 8 + h) * 64 + lr)) * SS + kof + lc;

    // prefetch tile 0
    v8bf ka  = *(const v8bf*)kbase;
    v8bf kb2 = *(const v8bf*)(kbase + 8);
    v8bf va  = *(const v8bf*)vbase;
    v8bf vb2 = *(const v8bf*)(vbase + 8);
    float mb = 0.f;
    if (t < 64) mb = mask[b * SS + kof + t] ? MBIAS : 0.f;

    float l_acc = 0.f;
    v4f o[4] = {};

    #pragma unroll 1
    for (int k0 = 0; k0 < KHALF; k0 += 64) {
        *(v8bf*)&Ks[lr][lc]     = ka;
        *(v8bf*)&Ks[lr][lc + 8] = kb2;
        *(v8bf*)&Vs[lr][lc]     = va;
        *(v8bf*)&Vs[lr][lc + 8] = vb2;
        if (t < 64) mkf[t] = mb;
        __syncthreads();
        if (k0 + 64 < KHALF) {   // prefetch next tile
            const __bf16* kp = kbase + (size_t)(k0 + 64) * EE;
            const __bf16* vp = vbase + (k0 + 64);
            ka  = *(const v8bf*)kp;
            kb2 = *(const v8bf*)(kp + 8);
            va  = *(const v8bf*)vp;
            vb2 = *(const v8bf*)(vp + 8);
            if (t < 64) mb = mask[b * SS + kof + k0 + 64 + t] ? MBIAS : 0.f;
        }

        // ---- S^T = K*Q^T : s4[j] holds true s = j*16+quad*4+r, q = l16
        v4f s4[4];
        #pragma unroll
        for (int j = 0; j < 4; ++j) {
            v8bf kf0 = *(const v8bf*)&Ks[j * 16 + l16][quad * 8];
            v8bf kf1 = *(const v8bf*)&Ks[j * 16 + l16][32 + quad * 8];
            v4f zz = {};
            zz = __builtin_amdgcn_mfma_f32_16x16x32_bf16(kf0, qa0, zz, 0, 0, 0);
            zz = __builtin_amdgcn_mfma_f32_16x16x32_bf16(kf1, qa1, zz, 0, 0, 0);
            s4[j] = zz;
        }
        float4 mk4[4];
        #pragma unroll
        for (int j = 0; j < 4; ++j) mk4[j] = *(const float4*)&mkf[j * 16 + quad * 4];

        // ---- p = exp2(s*scl + maskbias); pack DIRECTLY into PV B-operands
        v8bf pb0, pb1;
        float ts = 0.f;
        #pragma unroll
        for (int j = 0; j < 4; ++j) {
            float p0 = exp2f(fmaf(s4[j][0], SCL2, mk4[j].x));
            float p1 = exp2f(fmaf(s4[j][1], SCL2, mk4[j].y));
            float p2 = exp2f(fmaf(s4[j][2], SCL2, mk4[j].z));
            float p3 = exp2f(fmaf(s4[j][3], SCL2, mk4[j].w));
            ts += (p0 + p1) + (p2 + p3);
            if (j < 2) {
                pb0[j * 4 + 0] = (__bf16)p0; pb0[j * 4 + 1] = (__bf16)p1;
                pb0[j * 4 + 2] = (__bf16)p2; pb0[j * 4 + 3] = (__bf16)p3;
            } else {
                pb1[(j - 2) * 4 + 0] = (__bf16)p0; pb1[(j - 2) * 4 + 1] = (__bf16)p1;
                pb1[(j - 2) * 4 + 2] = (__bf16)p2; pb1[(j - 2) * 4 + 3] = (__bf16)p3;
            }
        }
        l_acc += ts;

        // ---- O^T += V^T * P^T : A=V^T (m=d, k=slot), B=P (k=slot, n=q=l16)
        #pragma unroll
        for (int dt = 0; dt < 4; ++dt) {
            v8bf vf0 = *(const v8bf*)&Vs[dt * 16 + l16][quad * 8];
            v8bf vf1 = *(const v8bf*)&Vs[dt * 16 + l16][32 + quad * 8];
            o[dt] = __builtin_amdgcn_mfma_f32_16x16x32_bf16(vf0, pb0, o[dt], 0, 0, 0);
            o[dt] = __builtin_amdgcn_mfma_f32_16x16x32_bf16(vf1, pb1, o[dt], 0, 0, 0);
        }
        __syncthreads();   // readers done before next restage
    }

    // row totals: sum l over the 4 quads holding this q-row
    l_acc += __shfl_xor(l_acc, 16, 64);
    l_acc += __shfl_xor(l_acc, 32, 64);

    // ---- epilogue: raw partial O^T (col=l16 -> q; row=quad*4+r -> d)
    const size_t qi = (size_t)(z * 16 + bh) * SS + (q0 + w * 16 + l16);
    __bf16* op = Opart + qi * 64;
    #pragma unroll
    for (int dt = 0; dt < 4; ++dt) {
        v4bf u;
        #pragma unroll
        for (int r = 0; r < 4; ++r) u[r] = (__bf16)o[dt][r];
        *(v4bf*)(op + dt * 16 + quad * 4) = u;
    }
    if (quad == 0) MLl[qi] = l_acc;
}

// --------------------------------------------------------------- launch
extern "C" void kernel_launch(void* const* d_in, const int* in_sizes, int n_in,
                              void* d_out, int out_size, void* d_ws, size_t ws_size,
                              hipStream_t stream) {
    const void* x_in = d_in[0];
    const int*  mask = (const int*)d_in[1];
    const void* wq = d_in[2];  const void* bq = d_in[3];
    const void* wk = d_in[4];  const void* bk = d_in[5];
    const void* wv = d_in[6];  const void* bv = d_in[7];
    const void* g1 = d_in[8];  const void* b1 = d_in[9];
    const void* g2 = d_in[10]; const void* b2 = d_in[11];
    const void* gf = d_in[12]; const void* bfp= d_in[13];
    const void* W1 = d_in[14]; const void* B1 = d_in[15];
    const void* W2 = d_in[16]; const void* B2 = d_in[17];

    // ws layout (float units), ~58 MB total:
    // X | Qb Kb Vtg Hb | weights | MLl | Opart/MID shared region (2*NE floats)
    float* base = (float*)d_ws;
    int*   flag = (int*)base;
    float* X   = base + 16;          // NE f32 residual (persistent)
    float* fQ  = X + NE;             // NE/2 floats (Qb)
    float* fK  = fQ + NE / 2;        // NE/2 floats (Kb)
    float* fV  = fK + NE / 2;        // NE/2 floats (Vt global, s-permuted)
    float* fH  = fV + NE / 2;        // NE/2 floats (Hb)
    float* fW  = fH + NE / 2;        // converted weights (contiguous)
    __bf16* Qb    = (__bf16*)fQ;
    __bf16* Kb    = (__bf16*)fK;
    __bf16* Vtg   = (__bf16*)fV;     // [ (b*8+h)*64 + d ][ s (permuted/64) ]
    __bf16* Hb    = (__bf16*)fH;
    __bf16* wqc = (__bf16*)fW;
    __bf16* wkc = wqc + 2 * EE * EE;
    __bf16* wvc = wkc + 2 * EE * EE;
    __bf16* W1c = wvc + 2 * EE * EE;
    __bf16* W2c = W1c + DFF_ * EE;
    float* MLl = (float*)(W2c + (size_t)EE * DFF_);   // KSPLIT*16*SS f32
    float* fO  = MLl + (size_t)KSPLIT * 16 * SS;
    __bf16* Opart = (__bf16*)fO;     // KSPLIT x 16 bh x 2048 x 64 bf16 = 16.8 MB
    __bf16* MID   = (__bf16*)fO;     // NTOK*DFF bf16 (same size region)

    sniff_kernel<<<1, 256, 0, stream>>>((const unsigned short*)x_in, flag);
    cvt_kernel<<<NE / 4 / 256, 256, 0, stream>>>(x_in, X, NE, flag);
    wcvt_all<<<1792, 256, 0, stream>>>(wq, wk, wv, W1, W2, wqc, flag);

    const dim3 gQKV(NTOK / 128, EE / 128, 3);      // 384 blocks
    const dim3 gF1 (NTOK / 128, DFF_ / 128, 1);    // 512 blocks
    const dim3 gF2 (NTOK / 128, EE / 128, 4);      // 512 blocks (split-K x4)
    const dim3 gAtt(SS / 64, BB * HH, KSPLIT);     // 2048 blocks (8/CU)

    for (int l = 0; l < 2; ++l) {
        const size_t wo = (size_t)l * EE * EE, bo = (size_t)l * EE;
        // h = LN(x,g1,b1) -> bf16
        ln_kernel<<<NTOK, 256, 0, stream>>>(X, g1, b1, Hb, nullptr, flag);
        // q,k,v fused; z==2 writes permuted V^T (flags|8)
        gemm_mfma<<<gQKV, 256, 0, stream>>>(Hb, wqc, wkc, wvc, bq, bk, bv,
            Qb, Kb, Vtg, nullptr, NTOK, EE, EE, 8, wo, bo, flag);
        // attention partials (raw sums + l)
        attn_mfma<<<gAtt, 256, 0, stream>>>(Qb, Kb, Vtg, mask, Opart, MLl);
        // combine partials; x += LN(att,g2,b2); h = LN_noaffine(x)
        combine_ln<<<NTOK, 256, 0, stream>>>(Opart, MLl, g2, b2, X, Hb, flag);
        // mid = relu(h @ W1^T + B1) -> bf16 (MID aliases dead Opart)
        gemm_mfma<<<gF1, 256, 0, stream>>>(Hb, W1c, W1c, W1c, B1, B1, B1,
            MID, MID, MID, nullptr, NTOK, DFF_, EE, 1, 0, 0, flag);
        // x += mid @ W2^T + B2  (split-K x4, atomic f32)
        gemm_mfma<<<gF2, 256, 0, stream>>>(MID, W2c, W2c, W2c, B2, B2, B2,
            nullptr, nullptr, nullptr, X, NTOK, EE, DFF_, 2 | 4, 0, 0, flag);
    }
    ln_kernel<<<NTOK, 256, 0, stream>>>(X, gf, bfp, nullptr, d_out, flag);
}

// Round 14
// 361.852 us; speedup vs baseline: 1.0267x; 1.0267x over previous
//
#include <hip/hip_runtime.h>
#include <hip/hip_bf16.h>

// Problem constants (B,S,E,H,L,DFF) = (2,2048,512,8,2,2048), D=64
constexpr int BB   = 2;
constexpr int SS   = 2048;
constexpr int EE   = 512;
constexpr int HH   = 8;
constexpr int DD   = 64;
constexpr int DFF_ = 2048;
constexpr int NTOK = BB * SS;          // 4096 tokens
constexpr int NE   = NTOK * EE;        // 2097152
constexpr float EPSF  = 1e-5f;
constexpr float SCL2  = 0.125f * 1.44269504088896f;  // 1/sqrt(D) * log2(e)
constexpr float MBIAS = -1e30f;
constexpr int KSPLIT = 2;              // attention split-K parts (R9/R12-proven)
constexpr int KHALF  = SS / KSPLIT;    // 1024

typedef __bf16 v8bf __attribute__((ext_vector_type(8)));
typedef __bf16 v4bf __attribute__((ext_vector_type(4)));
typedef float  v4f  __attribute__((ext_vector_type(4)));

__device__ __forceinline__ float bf2f(unsigned short u) {
    return __uint_as_float(((unsigned int)u) << 16);
}
__device__ __forceinline__ float bf2f(__bf16 u) {
    unsigned short us = __builtin_bit_cast(unsigned short, u);
    return __uint_as_float(((unsigned int)us) << 16);
}
// adaptive load: f=1 -> float32 buffer, f=0 -> bf16 buffer
__device__ __forceinline__ float ldA(const void* p, size_t i, int f) {
    return f ? ((const float*)p)[i] : bf2f(((const unsigned short*)p)[i]);
}
// async global->LDS, 16 B per lane (m97-verified path)
__device__ __forceinline__ void gll16(const void* g, void* l) {
    __builtin_amdgcn_global_load_lds(
        (const __attribute__((address_space(1))) void*)g,
        (__attribute__((address_space(3))) void*)l, 16, 0, 0);
}

// --------------------------------------------------------------- dtype sniff
__global__ void sniff_kernel(const unsigned short* __restrict__ x, int* flag) {
    __shared__ int cnt[256];
    int t = threadIdx.x, bad = 0;
    for (int i = t; i < 4096; i += 256) {
        float v = bf2f(x[i]);
        if (!(fabsf(v) < 1000.f)) bad++;
    }
    cnt[t] = bad;
    __syncthreads();
    if (t == 0) {
        int s = 0;
        for (int i = 0; i < 256; ++i) s += cnt[i];
        *flag = (s > 8) ? 1 : 0;           // 1 = inputs are float32
    }
}

// --------------------------------------------------------------- cvt x -> f32
__global__ void cvt_kernel(const void* __restrict__ in, float* __restrict__ out,
                           int n, const int* __restrict__ flagp) {
    const int f = *flagp;
    int i = (blockIdx.x * blockDim.x + threadIdx.x) * 4;
    if (i >= n) return;
    if (f) {
        *(float4*)(out + i) = *(const float4*)((const float*)in + i);
    } else {
        ushort4 u = *(const ushort4*)((const unsigned short*)in + i);
        out[i + 0] = bf2f(u.x); out[i + 1] = bf2f(u.y);
        out[i + 2] = bf2f(u.z); out[i + 3] = bf2f(u.w);
    }
}

// --------------------------------------------------------------- all weights -> bf16 (one launch)
__global__ void wcvt_all(const void* __restrict__ wq, const void* __restrict__ wk,
                         const void* __restrict__ wv, const void* __restrict__ W1,
                         const void* __restrict__ W2, __bf16* __restrict__ out,
                         const int* __restrict__ flagp) {
    const int f = *flagp;
    const int i = (blockIdx.x * blockDim.x + threadIdx.x) * 8;
    constexpr int n1 = 2 * EE * EE;      // 524288 per QKV tensor
    constexpr int nf = DFF_ * EE;        // 1048576 per FFN tensor
    const void* src; int off;
    if      (i < n1)          { src = wq; off = i; }
    else if (i < 2 * n1)      { src = wk; off = i - n1; }
    else if (i < 3 * n1)      { src = wv; off = i - 2 * n1; }
    else if (i < 3 * n1 + nf) { src = W1; off = i - 3 * n1; }
    else                      { src = W2; off = i - 3 * n1 - nf; }
    if (f) {
        const float* p = (const float*)src + off;
        #pragma unroll
        for (int j = 0; j < 8; ++j) out[i + j] = (__bf16)p[j];
    } else {
        *(uint4*)(out + i) = *(const uint4*)((const unsigned short*)src + off);
    }
}

// --------------------------------------------------------------- layernorm (single)
__global__ __launch_bounds__(256) void ln_kernel(
    const float* __restrict__ src,
    const void* __restrict__ g, const void* __restrict__ b,
    __bf16* __restrict__ dstb, void* __restrict__ outp,
    const int* __restrict__ flagp)
{
    const int f = *flagp;
    const int row = blockIdx.x, t = threadIdx.x;
    const float* x = src + (size_t)row * EE;
    float v0 = x[t], v1 = x[t + 256];
    float s = v0 + v1, q = v0 * v0 + v1 * v1;
    #pragma unroll
    for (int off = 32; off > 0; off >>= 1) {
        s += __shfl_down(s, off, 64);
        q += __shfl_down(q, off, 64);
    }
    __shared__ float red[8], st[2];
    const int wid = t >> 6;
    if ((t & 63) == 0) { red[wid] = s; red[4 + wid] = q; }
    __syncthreads();
    if (t == 0) {
        float S_ = red[0] + red[1] + red[2] + red[3];
        float Q_ = red[4] + red[5] + red[6] + red[7];
        float mu = S_ / EE;
        st[0] = mu;
        st[1] = rsqrtf(Q_ / EE - mu * mu + EPSF);
    }
    __syncthreads();
    const float mu = st[0], rs = st[1];
    float o0 = (v0 - mu) * rs, o1 = (v1 - mu) * rs;
    if (g) {
        o0 = o0 * ldA(g, t, f)       + ldA(b, t, f);
        o1 = o1 * ldA(g, t + 256, f) + ldA(b, t + 256, f);
    }
    const size_t i0 = (size_t)row * EE + t, i1 = i0 + 256;
    if (dstb) { dstb[i0] = (__bf16)o0; dstb[i1] = (__bf16)o1; }
    if (outp) {
        if (f) { ((float*)outp)[i0] = o0; ((float*)outp)[i1] = o1; }
        else {
            ((__hip_bfloat16*)outp)[i0] = __float2bfloat16(o0);
            ((__hip_bfloat16*)outp)[i1] = __float2bfloat16(o1);
        }
    }
}

// --------------------------------------------------------------- combine + residual + double LN
__global__ __launch_bounds__(256) void combine_ln(
    const __bf16* __restrict__ Opart, const float* __restrict__ MLl,
    const void* __restrict__ g2, const void* __restrict__ b2,
    float* __restrict__ X, __bf16* __restrict__ Hb,
    const int* __restrict__ flagp)
{
    const int f = *flagp;
    const int tok = blockIdx.x, t = threadIdx.x;
    const int b = tok >> 11, s_ = tok & 2047;
    __shared__ float cinv[8];
    __shared__ float red[8], st[2];
    if (t < 8) {
        float l = 0.f;
        #pragma unroll
        for (int zz = 0; zz < KSPLIT; ++zz)
            l += MLl[(size_t)(zz * 16 + b * 8 + t) * SS + s_];
        cinv[t] = (l > 0.f) ? 1.f / l : 0.f;
    }
    __syncthreads();
    float a0 = 0.f, a1 = 0.f;
    {
        int c = t, h = c >> 6, d = c & 63;
        #pragma unroll
        for (int zz = 0; zz < KSPLIT; ++zz)
            a0 += bf2f(Opart[((size_t)(zz * 16 + b * 8 + h) * SS + s_) * 64 + d]);
        a0 *= cinv[h];
        c = t + 256; h = c >> 6; d = c & 63;
        #pragma unroll
        for (int zz = 0; zz < KSPLIT; ++zz)
            a1 += bf2f(Opart[((size_t)(zz * 16 + b * 8 + h) * SS + s_) * 64 + d]);
        a1 *= cinv[h];
    }
    const int wid = t >> 6;
    {
        float s = a0 + a1, q = a0 * a0 + a1 * a1;
        #pragma unroll
        for (int off = 32; off > 0; off >>= 1) {
            s += __shfl_down(s, off, 64);
            q += __shfl_down(q, off, 64);
        }
        if ((t & 63) == 0) { red[wid] = s; red[4 + wid] = q; }
    }
    __syncthreads();
    if (t == 0) {
        float S_ = red[0] + red[1] + red[2] + red[3];
        float Q_ = red[4] + red[5] + red[6] + red[7];
        float mu = S_ / EE;
        st[0] = mu;
        st[1] = rsqrtf(Q_ / EE - mu * mu + EPSF);
    }
    __syncthreads();
    const float mu1 = st[0], rs1 = st[1];
    const size_t i0 = (size_t)tok * EE + t, i1 = i0 + 256;
    float l0v = (a0 - mu1) * rs1 * ldA(g2, t, f)       + ldA(b2, t, f);
    float l1v = (a1 - mu1) * rs1 * ldA(g2, t + 256, f) + ldA(b2, t + 256, f);
    float x0 = X[i0] + l0v, x1 = X[i1] + l1v;
    __syncthreads();
    {
        float s = x0 + x1, q = x0 * x0 + x1 * x1;
        #pragma unroll
        for (int off = 32; off > 0; off >>= 1) {
            s += __shfl_down(s, off, 64);
            q += __shfl_down(q, off, 64);
        }
        if ((t & 63) == 0) { red[wid] = s; red[4 + wid] = q; }
    }
    __syncthreads();
    if (t == 0) {
        float S_ = red[0] + red[1] + red[2] + red[3];
        float Q_ = red[4] + red[5] + red[6] + red[7];
        float mu = S_ / EE;
        st[0] = mu;
        st[1] = rsqrtf(Q_ / EE - mu * mu + EPSF);
    }
    __syncthreads();
    const float mu2 = st[0], rs2 = st[1];
    X[i0] = x0; X[i1] = x1;
    Hb[i0] = (__bf16)((x0 - mu2) * rs2);
    Hb[i1] = (__bf16)((x1 - mu2) * rs2);
}

// --------------------------------------------------------------- MFMA GEMM (NT), 128x128, double-buffered
// (R12-proven; 0.5 ds_read/MFMA)
__global__ __launch_bounds__(256) void gemm_mfma(
    const __bf16* __restrict__ A,
    const __bf16* Wa, const __bf16* Wb, const __bf16* Wc,
    const void* ba, const void* bb, const void* bc,
    __bf16* oa, __bf16* ob, __bf16* oc,
    float* __restrict__ Cf,
    int M, int N, int K, int flags,
    size_t welem_off, size_t belem_off, const int* __restrict__ flagp)
{
    const int f = *flagp;
    const int z = blockIdx.z;
    const __bf16* W = (z == 0) ? Wa : (z == 1) ? Wb : Wc;
    const void* bias = (z == 0) ? ba : (z == 1) ? bb : bc;
    __bf16* Cb = (z == 0) ? oa : (z == 1) ? ob : oc;
    W += welem_off;
    int kbeg = 0, kend = K;
    if (flags & 4) {
        const int ks = K >> 2;
        kbeg = z * ks; kend = kbeg + ks;
        if (z != 0) bias = nullptr;
    }

    __shared__ __bf16 As[2][128 * 32];   // 2 x 8 KB
    __shared__ __bf16 Bs[2][128 * 32];   // 2 x 8 KB
    const int t = threadIdx.x;
    const int w = t >> 6, lane = t & 63;
    const int quad = lane >> 4, l16 = lane & 15;
    const int wr = w >> 1, wc = w & 1;
    const int bm = blockIdx.x * 128, bn = blockIdx.y * 128;

    v4f acc[4][4] = {};
    const int c0 = t, c1 = t + 256;          // 512 16B chunks per tile
    const int r0 = c0 >> 2, e0 = (c0 & 3) * 8;
    const int r1 = c1 >> 2, e1 = (c1 & 3) * 8;

    // stage tile kbeg into buffer 0
    gll16(A + (size_t)(bm + r0) * K + kbeg + e0, (char*)As[0] + c0 * 16);
    gll16(A + (size_t)(bm + r1) * K + kbeg + e1, (char*)As[0] + c1 * 16);
    gll16(W + (size_t)(bn + r0) * K + kbeg + e0, (char*)Bs[0] + c0 * 16);
    gll16(W + (size_t)(bn + r1) * K + kbeg + e1, (char*)Bs[0] + c1 * 16);

    int p = 0;
    for (int k0 = kbeg; k0 < kend; k0 += 32) {
        __syncthreads();   // tile p staged (vmcnt drained at barrier); p^1 reads done
        if (k0 + 32 < kend) {
            const int kn = k0 + 32, q_ = p ^ 1;
            gll16(A + (size_t)(bm + r0) * K + kn + e0, (char*)As[q_] + c0 * 16);
            gll16(A + (size_t)(bm + r1) * K + kn + e1, (char*)As[q_] + c1 * 16);
            gll16(W + (size_t)(bn + r0) * K + kn + e0, (char*)Bs[q_] + c0 * 16);
            gll16(W + (size_t)(bn + r1) * K + kn + e1, (char*)Bs[q_] + c1 * 16);
        }
        v8bf af[4], bfr[4];
        #pragma unroll
        for (int i = 0; i < 4; ++i) {
            int row = wr * 64 + i * 16 + l16;
            af[i] = *(const v8bf*)&As[p][row * 32 + quad * 8];
        }
        #pragma unroll
        for (int j = 0; j < 4; ++j) {
            int row = wc * 64 + j * 16 + l16;
            bfr[j] = *(const v8bf*)&Bs[p][row * 32 + quad * 8];
        }
        #pragma unroll
        for (int i = 0; i < 4; ++i)
            #pragma unroll
            for (int j = 0; j < 4; ++j)
                acc[i][j] = __builtin_amdgcn_mfma_f32_16x16x32_bf16(
                    af[i], bfr[j], acc[i][j], 0, 0, 0);
        p ^= 1;
    }

    float bvv[4];
    #pragma unroll
    for (int j = 0; j < 4; ++j) {
        int col = bn + wc * 64 + j * 16 + l16;
        bvv[j] = bias ? ldA(bias, belem_off + col, f) : 0.f;
    }

    if ((flags & 8) && z == 2) {
        // V^T write with per-64-block s-permutation:
        // slot(s) = (s&32) + ((s>>2)&3)*8 + ((s>>4)&1)*4 + (s&3); r adds to low bits.
        #pragma unroll
        for (int i = 0; i < 4; ++i) {
            const int row0 = bm + wr * 64 + i * 16 + quad * 4;  // token (r=0)
            const int b_ = row0 >> 11, sl = row0 & 2047;
            const int s64 = sl & ~63, sloc = sl & 63;
            const int slot = (sloc & 32) + ((sloc >> 2) & 3) * 8 + ((sloc >> 4) & 1) * 4;
            #pragma unroll
            for (int j = 0; j < 4; ++j) {
                const int col = bn + wc * 64 + j * 16 + l16;
                const int h_ = col >> 6, d_ = col & 63;
                v4bf u;
                #pragma unroll
                for (int r = 0; r < 4; ++r) u[r] = (__bf16)(acc[i][j][r] + bvv[j]);
                *(v4bf*)(Cb + ((size_t)((b_ * 8 + h_) * 64 + d_)) * SS + s64 + slot) = u;
            }
        }
        return;
    }

    #pragma unroll
    for (int i = 0; i < 4; ++i) {
        const int rowb = bm + wr * 64 + i * 16 + quad * 4;
        #pragma unroll
        for (int j = 0; j < 4; ++j) {
            const int col = bn + wc * 64 + j * 16 + l16;
            #pragma unroll
            for (int r = 0; r < 4; ++r) {
                float v = acc[i][j][r] + bvv[j];
                if (flags & 1) v = fmaxf(v, 0.f);
                const size_t idx = (size_t)(rowb + r) * N + col;
                if (flags & 4)      unsafeAtomicAdd(&Cf[idx], v);
                else if (flags & 2) Cf[idx] += v;
                else                Cb[idx] = (__bf16)v;
            }
        }
    }
}

// --------------------------------------------------------------- MFMA attention (AQ=128, 8 waves)
// Transposed dataflow (S^T = K*Q^T), split-K x2, no max-tracking, PERMUTED-V.
// 512-thread blocks: 8 waves share each staged K/V tile (128 q-rows/block) —
// halves K/V fetch + staging + barrier cost per MFMA vs the 64-row version.
// R13 lesson: attention is invariant to block-count scaling (occupancy stuck
// ~28% from 1024->2048 blocks); the win is traffic amortization, not more blocks.
__global__ __launch_bounds__(512) void attn_mfma(
    const __bf16* __restrict__ Qg, const __bf16* __restrict__ Kg,
    const __bf16* __restrict__ Vtg, const int* __restrict__ mask,
    __bf16* __restrict__ Opart, float* __restrict__ MLl)
{
    __shared__ __bf16 Ks[64][72];     // [token][d]  (true s order)
    __shared__ __bf16 Vs[64][72];     // [d][slot]   (permuted s)
    __shared__ float  mkf[64];

    const int t = threadIdx.x;
    const int w = t >> 6, lane = t & 63;      // w in 0..7
    const int quad = lane >> 4, l16 = lane & 15;
    const int bh = blockIdx.y, b = bh >> 3, h = bh & 7;
    const int q0 = blockIdx.x * 128;
    const int z  = blockIdx.z;
    const int kof = z * KHALF;

    // Q fragments (B-operand of S^T: n=l16 -> q-row, k=quad*8+j -> d)
    const __bf16* qrow = Qg + ((size_t)(b * SS + q0 + w * 16 + l16)) * EE + h * DD + quad * 8;
    const v8bf qa0 = *(const v8bf*)qrow;
    const v8bf qa1 = *(const v8bf*)(qrow + 32);

    // loader mapping: 512 threads, one v8bf each: row lr (0..63), chunk lc
    const int lr = t >> 3, lc = (t & 7) * 8;
    const __bf16* kbase = Kg  + ((size_t)(b * SS + kof + lr)) * EE + h * DD + lc;
    const __bf16* vbase = Vtg + ((size_t)((b * 8 + h) * 64 + lr)) * SS + kof + lc;

    // prefetch tile 0
    v8bf ka = *(const v8bf*)kbase;
    v8bf va = *(const v8bf*)vbase;
    float mb = 0.f;
    if (t < 64) mb = mask[b * SS + kof + t] ? MBIAS : 0.f;

    float l_acc = 0.f;
    v4f o[4] = {};

    #pragma unroll 1
    for (int k0 = 0; k0 < KHALF; k0 += 64) {
        *(v8bf*)&Ks[lr][lc] = ka;
        *(v8bf*)&Vs[lr][lc] = va;
        if (t < 64) mkf[t] = mb;
        __syncthreads();
        if (k0 + 64 < KHALF) {   // prefetch next tile
            ka = *(const v8bf*)(kbase + (size_t)(k0 + 64) * EE);
            va = *(const v8bf*)(vbase + (k0 + 64));
            if (t < 64) mb = mask[b * SS + kof + k0 + 64 + t] ? MBIAS : 0.f;
        }

        // ---- S^T = K*Q^T : s4[j] holds true s = j*16+quad*4+r, q = l16
        v4f s4[4];
        #pragma unroll
        for (int j = 0; j < 4; ++j) {
            v8bf kf0 = *(const v8bf*)&Ks[j * 16 + l16][quad * 8];
            v8bf kf1 = *(const v8bf*)&Ks[j * 16 + l16][32 + quad * 8];
            v4f zz = {};
            zz = __builtin_amdgcn_mfma_f32_16x16x32_bf16(kf0, qa0, zz, 0, 0, 0);
            zz = __builtin_amdgcn_mfma_f32_16x16x32_bf16(kf1, qa1, zz, 0, 0, 0);
            s4[j] = zz;
        }
        float4 mk4[4];
        #pragma unroll
        for (int j = 0; j < 4; ++j) mk4[j] = *(const float4*)&mkf[j * 16 + quad * 4];

        // ---- p = exp2(s*scl + maskbias); pack DIRECTLY into PV B-operands
        v8bf pb0, pb1;
        float ts = 0.f;
        #pragma unroll
        for (int j = 0; j < 4; ++j) {
            float p0 = exp2f(fmaf(s4[j][0], SCL2, mk4[j].x));
            float p1 = exp2f(fmaf(s4[j][1], SCL2, mk4[j].y));
            float p2 = exp2f(fmaf(s4[j][2], SCL2, mk4[j].z));
            float p3 = exp2f(fmaf(s4[j][3], SCL2, mk4[j].w));
            ts += (p0 + p1) + (p2 + p3);
            if (j < 2) {
                pb0[j * 4 + 0] = (__bf16)p0; pb0[j * 4 + 1] = (__bf16)p1;
                pb0[j * 4 + 2] = (__bf16)p2; pb0[j * 4 + 3] = (__bf16)p3;
            } else {
                pb1[(j - 2) * 4 + 0] = (__bf16)p0; pb1[(j - 2) * 4 + 1] = (__bf16)p1;
                pb1[(j - 2) * 4 + 2] = (__bf16)p2; pb1[(j - 2) * 4 + 3] = (__bf16)p3;
            }
        }
        l_acc += ts;

        // ---- O^T += V^T * P^T : A=V^T (m=d, k=slot), B=P (k=slot, n=q=l16)
        #pragma unroll
        for (int dt = 0; dt < 4; ++dt) {
            v8bf vf0 = *(const v8bf*)&Vs[dt * 16 + l16][quad * 8];
            v8bf vf1 = *(const v8bf*)&Vs[dt * 16 + l16][32 + quad * 8];
            o[dt] = __builtin_amdgcn_mfma_f32_16x16x32_bf16(vf0, pb0, o[dt], 0, 0, 0);
            o[dt] = __builtin_amdgcn_mfma_f32_16x16x32_bf16(vf1, pb1, o[dt], 0, 0, 0);
        }
        __syncthreads();   // readers done before next restage
    }

    // row totals: sum l over the 4 quads holding this q-row
    l_acc += __shfl_xor(l_acc, 16, 64);
    l_acc += __shfl_xor(l_acc, 32, 64);

    // ---- epilogue: raw partial O^T (col=l16 -> q; row=quad*4+r -> d)
    const size_t qi = (size_t)(z * 16 + bh) * SS + (q0 + w * 16 + l16);
    __bf16* op = Opart + qi * 64;
    #pragma unroll
    for (int dt = 0; dt < 4; ++dt) {
        v4bf u;
        #pragma unroll
        for (int r = 0; r < 4; ++r) u[r] = (__bf16)o[dt][r];
        *(v4bf*)(op + dt * 16 + quad * 4) = u;
    }
    if (quad == 0) MLl[qi] = l_acc;
}

// --------------------------------------------------------------- launch
extern "C" void kernel_launch(void* const* d_in, const int* in_sizes, int n_in,
                              void* d_out, int out_size, void* d_ws, size_t ws_size,
                              hipStream_t stream) {
    const void* x_in = d_in[0];
    const int*  mask = (const int*)d_in[1];
    const void* wq = d_in[2];  const void* bq = d_in[3];
    const void* wk = d_in[4];  const void* bk = d_in[5];
    const void* wv = d_in[6];  const void* bv = d_in[7];
    const void* g1 = d_in[8];  const void* b1 = d_in[9];
    const void* g2 = d_in[10]; const void* b2 = d_in[11];
    const void* gf = d_in[12]; const void* bfp= d_in[13];
    const void* W1 = d_in[14]; const void* B1 = d_in[15];
    const void* W2 = d_in[16]; const void* B2 = d_in[17];

    // ws layout (float units), ~50 MB total:
    // X | Qb Kb Vtg Hb | weights | MLl | Opart/MID shared region (2*NE floats)
    float* base = (float*)d_ws;
    int*   flag = (int*)base;
    float* X   = base + 16;          // NE f32 residual (persistent)
    float* fQ  = X + NE;             // NE/2 floats (Qb)
    float* fK  = fQ + NE / 2;        // NE/2 floats (Kb)
    float* fV  = fK + NE / 2;        // NE/2 floats (Vt global, s-permuted)
    float* fH  = fV + NE / 2;        // NE/2 floats (Hb)
    float* fW  = fH + NE / 2;        // converted weights (contiguous)
    __bf16* Qb    = (__bf16*)fQ;
    __bf16* Kb    = (__bf16*)fK;
    __bf16* Vtg   = (__bf16*)fV;     // [ (b*8+h)*64 + d ][ s (permuted/64) ]
    __bf16* Hb    = (__bf16*)fH;
    __bf16* wqc = (__bf16*)fW;
    __bf16* wkc = wqc + 2 * EE * EE;
    __bf16* wvc = wkc + 2 * EE * EE;
    __bf16* W1c = wvc + 2 * EE * EE;
    __bf16* W2c = W1c + DFF_ * EE;
    float* MLl = (float*)(W2c + (size_t)EE * DFF_);   // KSPLIT*16*SS f32
    float* fO  = MLl + (size_t)KSPLIT * 16 * SS;
    __bf16* Opart = (__bf16*)fO;     // KSPLIT x 16 bh x 2048 x 64 bf16
    __bf16* MID   = (__bf16*)fO;     // NTOK*DFF bf16 (region sized for MID: 2*NE floats)

    sniff_kernel<<<1, 256, 0, stream>>>((const unsigned short*)x_in, flag);
    cvt_kernel<<<NE / 4 / 256, 256, 0, stream>>>(x_in, X, NE, flag);
    wcvt_all<<<1792, 256, 0, stream>>>(wq, wk, wv, W1, W2, wqc, flag);

    const dim3 gQKV(NTOK / 128, EE / 128, 3);      // 384 blocks
    const dim3 gF1 (NTOK / 128, DFF_ / 128, 1);    // 512 blocks
    const dim3 gF2 (NTOK / 128, EE / 128, 4);      // 512 blocks (split-K x4)
    const dim3 gAtt(SS / 128, BB * HH, KSPLIT);    // 512 blocks x 8 waves

    for (int l = 0; l < 2; ++l) {
        const size_t wo = (size_t)l * EE * EE, bo = (size_t)l * EE;
        // h = LN(x,g1,b1) -> bf16
        ln_kernel<<<NTOK, 256, 0, stream>>>(X, g1, b1, Hb, nullptr, flag);
        // q,k,v fused; z==2 writes permuted V^T (flags|8)
        gemm_mfma<<<gQKV, 256, 0, stream>>>(Hb, wqc, wkc, wvc, bq, bk, bv,
            Qb, Kb, Vtg, nullptr, NTOK, EE, EE, 8, wo, bo, flag);
        // attention partials (raw sums + l), 512-thread blocks
        attn_mfma<<<gAtt, 512, 0, stream>>>(Qb, Kb, Vtg, mask, Opart, MLl);
        // combine partials; x += LN(att,g2,b2); h = LN_noaffine(x)
        combine_ln<<<NTOK, 256, 0, stream>>>(Opart, MLl, g2, b2, X, Hb, flag);
        // mid = relu(h @ W1^T + B1) -> bf16 (MID aliases dead Opart)
        gemm_mfma<<<gF1, 256, 0, stream>>>(Hb, W1c, W1c, W1c, B1, B1, B1,
            MID, MID, MID, nullptr, NTOK, DFF_, EE, 1, 0, 0, flag);
        // x += mid @ W2^T + B2  (split-K x4, atomic f32)
        gemm_mfma<<<gF2, 256, 0, stream>>>(MID, W2c, W2c, W2c, B2, B2, B2,
            nullptr, nullptr, nullptr, X, NTOK, EE, DFF_, 2 | 4, 0, 0, flag);
    }
    ln_kernel<<<NTOK, 256, 0, stream>>>(X, gf, bfp, nullptr, d_out, flag);
}